// Round 9
// baseline (707.247 us; speedup 1.0000x reference)
//
#include <hip/hip_runtime.h>
#include <stdint.h>

#define IN_C 256
#define OUT_C 256
#define HH 56
#define WW 56
#define NB 32
#define HP 58
#define WP 58

#define NTILE 1792       // 32 img * 28 row-pairs * 2 oc-halves = 8*224
#define XCH 1856         // slab chunks: 4 rows * 58 cols * 8
#define XSHORTS 14848    // 4*58*64 shorts = 29696 B

typedef __attribute__((ext_vector_type(8))) short short8;
typedef __attribute__((ext_vector_type(4))) float float4_t;

typedef const __attribute__((address_space(1))) unsigned int guint_t;
typedef __attribute__((address_space(3))) unsigned int luint_t;

__device__ __forceinline__ unsigned short f2bf(float f) {
    union { float f; unsigned u; } v; v.f = f;
    unsigned r = v.u + 0x7FFF + ((v.u >> 16) & 1);   // RNE
    return (unsigned short)(r >> 16);
}

__device__ __forceinline__ void gload16(void* lds, const void* g) {
    __builtin_amdgcn_global_load_lds((guint_t*)g, (luint_t*)lds, 16, 0, 0);
}

// ---------------- pre-pass 1: NCHW f32 -> padded NHWC bf16 ----------------
__global__ __launch_bounds__(256) void pad_nhwc(const float* __restrict__ x,
                                                unsigned short* __restrict__ xpad) {
    __shared__ float lds[WW * 257];
    int bid = blockIdx.x;
    int n = bid / HP, h = bid % HP;
    unsigned short* dstRow = xpad + (size_t)(n * HP + h) * WP * IN_C;
    bool hin = (h >= 1 && h <= HH);
    if (hin) {
        const float* src = x + (size_t)n * IN_C * (HH * WW) + (h - 1) * WW;
        for (int e = threadIdx.x; e < IN_C * WW; e += 256) {
            int ic = e / WW, w = e - ic * WW;
            lds[w * 257 + ic] = src[(size_t)ic * (HH * WW) + w];
        }
    }
    __syncthreads();
    for (int e = threadIdx.x; e < WP * (IN_C / 8); e += 256) {
        int wo = e / (IN_C / 8);
        int icc = e - wo * (IN_C / 8);
        short8 v = {0, 0, 0, 0, 0, 0, 0, 0};
        if (hin && wo >= 1 && wo <= WW) {
            const float* p = &lds[(wo - 1) * 257 + icc * 8];
#pragma unroll
            for (int j = 0; j < 8; ++j) v[j] = (short)f2bf(p[j]);
        }
        *(short8*)(dstRow + wo * IN_C + icc * 8) = v;
    }
}

// ---------- pre-pass 2: OIHW f32 -> A-frag-ready wfr, chunk i = [qt][s8][ks][af][lane] ----------
// i = qt*2048 + s8*256 + ks*128 + af*64 + lane  (chunks of 8 bf16)
// element: oc = s8*32 + af*16 + (lane&15), ic = q*64 + ks*32 + (lane>>4)*8 + j, tap = qt%9
__global__ __launch_bounds__(256) void wconv(const float* __restrict__ w,
                                             unsigned short* __restrict__ wfr) {
    int i = blockIdx.x * 256 + threadIdx.x;      // 73728 chunks
    int lane = i & 63;
    int af = (i >> 6) & 1;
    int ks = (i >> 7) & 1;
    int s8 = (i >> 8) & 7;
    int qt = i >> 11;                            // 0..35
    int tap = qt % 9;
    int q = qt / 9;
    int oc = s8 * 32 + af * 16 + (lane & 15);
    int icb = q * 64 + ks * 32 + (lane >> 4) * 8;
    unsigned short* dst = wfr + (size_t)i * 8;
#pragma unroll
    for (int j = 0; j < 8; ++j)
        dst[j] = f2bf(w[((size_t)oc * 256 + icb + j) * 9 + tap]);
}

// ---------------- main: 4-wave blocks (32oc x 112px per wave), 5 blocks/CU ----------------
__global__ __launch_bounds__(256, 5) void conv_mfma(const unsigned short* __restrict__ xpad,
                                                    const unsigned short* __restrict__ wfr,
                                                    float* __restrict__ out) {
    __shared__ unsigned short Xl[XSHORTS];   // 4 rows x 58 cols x 64 ic, chunk-swizzled

    const int tid = threadIdx.x;
    const int lane = tid & 63;
    const int wid = tid >> 6;                // 0..3 : 32-oc slice within the half

    const int bid = blockIdx.x;
    const int xcd = bid & 7, loc = bid >> 3;         // 4 images per XCD
    const int n = xcd * 4 + loc / 56;
    const int r = loc % 56;
    const int h = r & 1;                     // oc half (0/1); halves of same px-tile adjacent
    const int rg = r >> 1;
    const int oh0 = rg * 2;                  // padded rows oh0..oh0+3
    const int pix0 = rg * 112;

    const unsigned short* xpn = xpad + (size_t)n * HP * WP * IN_C;

    // ---- X staging addressing (8 chunks/thread), rule #21 swizzle ----
    int xgo[8];
#pragma unroll
    for (int k = 0; k < 8; ++k) {
        int ci = tid + k * 256; if (ci > XCH - 1) ci = XCH - 1;
        int rc = ci >> 3, pc = ci & 7;
        int row = rc / 58, col = rc - row * 58;
        xgo[k] = ((oh0 + row) * WP + col) * IN_C + (pc ^ (col & 7)) * 8;
    }

    // ---- B-frag addressing ----
    const int rlo = lane & 15;
    const int kq = lane >> 4;
    int rcb[7], owl[7];
#pragma unroll
    for (int xf = 0; xf < 7; ++xf) {
        int pl = xf * 16 + rlo;              // 0..111
        int ohr = (pl >= 56) ? 1 : 0;
        int ow = pl - 56 * ohr;
        rcb[xf] = (ohr * 58 + ow) * 128;     // byte offset of cell
        owl[xf] = ow & 7;
    }

    // ---- A-frag base: chunks [qt][s8][ks][af][lane], s8 = h*4+wid ----
    const unsigned short* wbase = wfr + (size_t)((h * 4 + wid) * 256 + lane) * 8;

    float4_t acc[2][7];
#pragma unroll
    for (int af = 0; af < 2; ++af)
#pragma unroll
        for (int xf = 0; xf < 7; ++xf) acc[af][xf] = {0.f, 0.f, 0.f, 0.f};

    short8 A0[2], A1[2], Bf[7];

#define LOAD_A(AF, QT, KS)                                                        \
    {                                                                              \
        const unsigned short* p_ = wbase + (size_t)((QT)*2048 + (KS)*128) * 8;     \
        AF[0] = *(const short8*)p_;                                                \
        AF[1] = *(const short8*)(p_ + 512);                                        \
    }

#define READ_B(TAP, KS)                                                           \
    {                                                                              \
        const int tsh_ = (((TAP) / 3) * 58 + ((TAP) % 3)) * 128;                   \
        _Pragma("unroll")                                                          \
        for (int xf_ = 0; xf_ < 7; ++xf_) {                                        \
            int ch_ = ((kq + (KS)*4) ^ ((owl[xf_] + ((TAP) % 3)) & 7)) * 16;       \
            Bf[xf_] = *(const short8*)((const char*)Xl + rcb[xf_] + tsh_ + ch_);   \
        }                                                                          \
    }

#define MMA(AF)                                                                   \
    {                                                                              \
        __builtin_amdgcn_s_setprio(1);                                             \
        _Pragma("unroll")                                                          \
        for (int xf_ = 0; xf_ < 7; ++xf_)                                          \
            _Pragma("unroll")                                                      \
            for (int af_ = 0; af_ < 2; ++af_)                                      \
                acc[af_][xf_] = __builtin_amdgcn_mfma_f32_16x16x32_bf16(           \
                    AF[af_], Bf[xf_], acc[af_][xf_], 0, 0, 0);                     \
        __builtin_amdgcn_s_setprio(0);                                             \
    }

    LOAD_A(A0, 0, 0);   // q=0, tap=0, ks=0

    for (int q = 0; q < 4; ++q) {
        // ---- stage X slab for this q (single-buffered; TLP covers the drain) ----
        if (q) __builtin_amdgcn_s_barrier();          // all waves done reading prev slab
#pragma unroll
        for (int k = 0; k < 7; ++k)
            gload16(&Xl[(tid + k * 256) * 8], xpn + xgo[k] + q * 64);
        if (tid < XCH - 1792)
            gload16(&Xl[(tid + 1792) * 8], xpn + xgo[7] + q * 64);
        asm volatile("s_waitcnt vmcnt(0)" ::: "memory");
        __builtin_amdgcn_s_barrier();
        __builtin_amdgcn_sched_barrier(0);

        const int qt0 = q * 9;
#pragma unroll
        for (int s = 0; s < 18; ++s) {
            const int tap = s >> 1, ks = s & 1;
            // prefetch next step's A-frags into the other set
            if (s < 17) {
                if (s & 1) { LOAD_A(A0, qt0 + ((s + 1) >> 1), (s + 1) & 1); }
                else       { LOAD_A(A1, qt0 + ((s + 1) >> 1), (s + 1) & 1); }
            } else if (q < 3) {
                LOAD_A(A0, qt0 + 9, 0);               // first step of next q (even parity)
            }
            READ_B(tap, ks);
            __builtin_amdgcn_sched_barrier(0);
            if (s & 1) { MMA(A1); }
            else       { MMA(A0); }
        }
    }

    // ---- epilogue: col = lane&15 -> pixel, row = kq*4+reg -> oc; xf innermost ----
    float* outn = out + (size_t)n * (OUT_C * HH * WW) + pix0 + rlo;
    const int ocb = h * 128 + wid * 32 + kq * 4;
#pragma unroll
    for (int af = 0; af < 2; ++af)
#pragma unroll
        for (int rr = 0; rr < 4; ++rr) {
            float* op = outn + (size_t)(ocb + af * 16 + rr) * (HH * WW);
#pragma unroll
            for (int xf = 0; xf < 7; ++xf)
                op[xf * 16] = acc[af][xf][rr];
        }
}

extern "C" void kernel_launch(void* const* d_in, const int* in_sizes, int n_in,
                              void* d_out, int out_size, void* d_ws, size_t ws_size,
                              hipStream_t stream) {
    const float* x = (const float*)d_in[0];
    const float* wgt = (const float*)d_in[1];
    float* out = (float*)d_out;

    unsigned short* xpad = (unsigned short*)d_ws;                       // 55.1 MB
    size_t xpad_bytes = (size_t)NB * HP * WP * IN_C * 2;
    unsigned short* wfr = (unsigned short*)((char*)d_ws + xpad_bytes);  // 1.18 MB

    hipLaunchKernelGGL(pad_nhwc, dim3(NB * HP), dim3(256), 0, stream, x, xpad);
    hipLaunchKernelGGL(wconv, dim3(288), dim3(256), 0, stream, wgt, wfr);
    hipLaunchKernelGGL(conv_mfma, dim3(NTILE), dim3(256), 0, stream, xpad, wfr, out);
}

// Round 10
// 150.861 us; speedup vs baseline: 4.6881x; 4.6881x over previous
//
#include <hip/hip_runtime.h>
#include <stdint.h>

#define IN_C 256
#define OUT_C 256
#define HH 56
#define WW 56
#define NB 32
#define HP 58
#define WP 58

#define NTILE 1792       // 32 img * 28 row-pairs * 2 oc-halves = 8*224
#define XCH 1856         // slab chunks: 4 rows * 58 cols * 8
#define XSHORTS 14848    // 4*58*64 shorts = 29696 B

typedef __attribute__((ext_vector_type(8))) short short8;
typedef __attribute__((ext_vector_type(4))) float float4_t;

typedef const __attribute__((address_space(1))) unsigned int guint_t;
typedef __attribute__((address_space(3))) unsigned int luint_t;

__device__ __forceinline__ unsigned short f2bf(float f) {
    union { float f; unsigned u; } v; v.f = f;
    unsigned r = v.u + 0x7FFF + ((v.u >> 16) & 1);   // RNE
    return (unsigned short)(r >> 16);
}

__device__ __forceinline__ void gload16(void* lds, const void* g) {
    __builtin_amdgcn_global_load_lds((guint_t*)g, (luint_t*)lds, 16, 0, 0);
}

// ---------------- pre-pass 1: NCHW f32 -> padded NHWC bf16 ----------------
__global__ __launch_bounds__(256) void pad_nhwc(const float* __restrict__ x,
                                                unsigned short* __restrict__ xpad) {
    __shared__ float lds[WW * 257];
    int bid = blockIdx.x;
    int n = bid / HP, h = bid % HP;
    unsigned short* dstRow = xpad + (size_t)(n * HP + h) * WP * IN_C;
    bool hin = (h >= 1 && h <= HH);
    if (hin) {
        const float* src = x + (size_t)n * IN_C * (HH * WW) + (h - 1) * WW;
        for (int e = threadIdx.x; e < IN_C * WW; e += 256) {
            int ic = e / WW, w = e - ic * WW;
            lds[w * 257 + ic] = src[(size_t)ic * (HH * WW) + w];
        }
    }
    __syncthreads();
    for (int e = threadIdx.x; e < WP * (IN_C / 8); e += 256) {
        int wo = e / (IN_C / 8);
        int icc = e - wo * (IN_C / 8);
        short8 v = {0, 0, 0, 0, 0, 0, 0, 0};
        if (hin && wo >= 1 && wo <= WW) {
            const float* p = &lds[(wo - 1) * 257 + icc * 8];
#pragma unroll
            for (int j = 0; j < 8; ++j) v[j] = (short)f2bf(p[j]);
        }
        *(short8*)(dstRow + wo * IN_C + icc * 8) = v;
    }
}

// ---------- pre-pass 2: OIHW f32 -> A-frag-ready wfr, chunk i = [qt][s8][ks][af][lane] ----------
__global__ __launch_bounds__(256) void wconv(const float* __restrict__ w,
                                             unsigned short* __restrict__ wfr) {
    int i = blockIdx.x * 256 + threadIdx.x;      // 73728 chunks
    int lane = i & 63;
    int af = (i >> 6) & 1;
    int ks = (i >> 7) & 1;
    int s8 = (i >> 8) & 7;
    int qt = i >> 11;                            // 0..35
    int tap = qt % 9;
    int q = qt / 9;
    int oc = s8 * 32 + af * 16 + (lane & 15);
    int icb = q * 64 + ks * 32 + (lane >> 4) * 8;
    unsigned short* dst = wfr + (size_t)i * 8;
#pragma unroll
    for (int j = 0; j < 8; ++j)
        dst[j] = f2bf(w[((size_t)oc * 256 + icb + j) * 9 + tap]);
}

// ---------------- main: 4-wave blocks (32oc x 112px per wave), 3 blocks/CU ----------------
__global__ __launch_bounds__(256, 3) void conv_mfma(const unsigned short* __restrict__ xpad,
                                                    const unsigned short* __restrict__ wfr,
                                                    float* __restrict__ out) {
    __shared__ unsigned short Xl[XSHORTS];   // 4 rows x 58 cols x 64 ic, chunk-swizzled

    const int tid = threadIdx.x;
    const int lane = tid & 63;
    const int wid = tid >> 6;                // 0..3 : 32-oc slice within the half

    const int bid = blockIdx.x;
    const int xcd = bid & 7, loc = bid >> 3;         // 4 images per XCD
    const int n = xcd * 4 + loc / 56;
    const int r = loc % 56;
    const int h = r & 1;                     // oc half (0/1)
    const int rg = r >> 1;
    const int oh0 = rg * 2;                  // padded rows oh0..oh0+3
    const int pix0 = rg * 112;

    const unsigned short* xpn = xpad + (size_t)n * HP * WP * IN_C;

    // ---- X staging addressing (8 chunks/thread), rule #21 swizzle ----
    int xgo[8];
#pragma unroll
    for (int k = 0; k < 8; ++k) {
        int ci = tid + k * 256; if (ci > XCH - 1) ci = XCH - 1;
        int rc = ci >> 3, pc = ci & 7;
        int row = rc / 58, col = rc - row * 58;
        xgo[k] = ((oh0 + row) * WP + col) * IN_C + (pc ^ (col & 7)) * 8;
    }

    // ---- B-frag addressing ----
    const int rlo = lane & 15;
    const int kq = lane >> 4;
    int rcb[7], owl[7];
#pragma unroll
    for (int xf = 0; xf < 7; ++xf) {
        int pl = xf * 16 + rlo;              // 0..111
        int ohr = (pl >= 56) ? 1 : 0;
        int ow = pl - 56 * ohr;
        rcb[xf] = (ohr * 58 + ow) * 128;     // byte offset of cell
        owl[xf] = ow & 7;
    }

    // ---- A-frag base: chunks [qt][s8][ks][af][lane], s8 = h*4+wid ----
    const unsigned short* wbase = wfr + (size_t)((h * 4 + wid) * 256 + lane) * 8;

    float4_t acc[2][7];
#pragma unroll
    for (int af = 0; af < 2; ++af)
#pragma unroll
        for (int xf = 0; xf < 7; ++xf) acc[af][xf] = {0.f, 0.f, 0.f, 0.f};

    short8 A0[2], A1[2], B0[7], B1[7];

#define LOAD_A(AF, QT, KS)                                                        \
    {                                                                              \
        const unsigned short* p_ = wbase + (size_t)((QT)*2048 + (KS)*128) * 8;     \
        AF[0] = *(const short8*)p_;                                                \
        AF[1] = *(const short8*)(p_ + 512);                                        \
    }

#define READ_B(BF, TAP, KS)                                                       \
    {                                                                              \
        const int tsh_ = (((TAP) / 3) * 58 + ((TAP) % 3)) * 128;                   \
        _Pragma("unroll")                                                          \
        for (int xf_ = 0; xf_ < 7; ++xf_) {                                        \
            int ch_ = ((kq + (KS)*4) ^ ((owl[xf_] + ((TAP) % 3)) & 7)) * 16;       \
            BF[xf_] = *(const short8*)((const char*)Xl + rcb[xf_] + tsh_ + ch_);   \
        }                                                                          \
    }

#define MMA(AF, BF)                                                               \
    {                                                                              \
        __builtin_amdgcn_s_setprio(1);                                             \
        _Pragma("unroll")                                                          \
        for (int xf_ = 0; xf_ < 7; ++xf_)                                          \
            _Pragma("unroll")                                                      \
            for (int af_ = 0; af_ < 2; ++af_)                                      \
                acc[af_][xf_] = __builtin_amdgcn_mfma_f32_16x16x32_bf16(           \
                    AF[af_], BF[xf_], acc[af_][xf_], 0, 0, 0);                     \
        __builtin_amdgcn_s_setprio(0);                                             \
    }

    LOAD_A(A0, 0, 0);   // q=0, tap=0, ks=0

    for (int q = 0; q < 4; ++q) {
        // ---- stage X slab for this q (single-buffered; TLP covers the drain) ----
        if (q) __builtin_amdgcn_s_barrier();          // all waves done reading prev slab
#pragma unroll
        for (int k = 0; k < 7; ++k)
            gload16(&Xl[(tid + k * 256) * 8], xpn + xgo[k] + q * 64);
        if (tid < XCH - 1792)
            gload16(&Xl[(tid + 1792) * 8], xpn + xgo[7] + q * 64);
        asm volatile("s_waitcnt vmcnt(0)" ::: "memory");
        __builtin_amdgcn_s_barrier();
        __builtin_amdgcn_sched_barrier(0);

        const int qt0 = q * 9;
        READ_B(B0, 0, 0);                             // first step's B (in-step, 1x per q)
#pragma unroll
        for (int s = 0; s < 18; ++s) {
            const int s1 = s + 1;
            // prefetch next step's A and B frags into the other set
            if (s < 17) {
                if (s & 1) { LOAD_A(A0, qt0 + (s1 >> 1), s1 & 1); READ_B(B0, s1 >> 1, s1 & 1); }
                else       { LOAD_A(A1, qt0 + (s1 >> 1), s1 & 1); READ_B(B1, s1 >> 1, s1 & 1); }
            } else if (q < 3) {
                LOAD_A(A0, qt0 + 9, 0);               // first step of next q (even parity)
            }
            __builtin_amdgcn_sched_barrier(0);
            if (s & 1) { MMA(A1, B1); }
            else       { MMA(A0, B0); }
        }
    }

    // ---- epilogue: col = lane&15 -> pixel, row = kq*4+reg -> oc; xf innermost ----
    float* outn = out + (size_t)n * (OUT_C * HH * WW) + pix0 + rlo;
    const int ocb = h * 128 + wid * 32 + kq * 4;
#pragma unroll
    for (int af = 0; af < 2; ++af)
#pragma unroll
        for (int rr = 0; rr < 4; ++rr) {
            float* op = outn + (size_t)(ocb + af * 16 + rr) * (HH * WW);
#pragma unroll
            for (int xf = 0; xf < 7; ++xf)
                op[xf * 16] = acc[af][xf][rr];
        }
}

extern "C" void kernel_launch(void* const* d_in, const int* in_sizes, int n_in,
                              void* d_out, int out_size, void* d_ws, size_t ws_size,
                              hipStream_t stream) {
    const float* x = (const float*)d_in[0];
    const float* wgt = (const float*)d_in[1];
    float* out = (float*)d_out;

    unsigned short* xpad = (unsigned short*)d_ws;                       // 55.1 MB
    size_t xpad_bytes = (size_t)NB * HP * WP * IN_C * 2;
    unsigned short* wfr = (unsigned short*)((char*)d_ws + xpad_bytes);  // 1.18 MB

    hipLaunchKernelGGL(pad_nhwc, dim3(NB * HP), dim3(256), 0, stream, x, xpad);
    hipLaunchKernelGGL(wconv, dim3(288), dim3(256), 0, stream, wgt, wfr);
    hipLaunchKernelGGL(conv_mfma, dim3(NTILE), dim3(256), 0, stream, xpad, wfr, out);
}

// Round 11
// 86.291 us; speedup vs baseline: 8.1960x; 1.7483x over previous
//
#include <hip/hip_runtime.h>
#include <stdint.h>

#define IN_C 256
#define OUT_C 256
#define HH 56
#define WW 56
#define NB 32
#define HP 58
#define WP 58

#define NTILE 1792          // 32 img * 28 row-pairs * 2 oc-halves
#define ROW_B 3712          // 58 cols * 64 B
#define QPLANE_B 215296     // 58 rows * ROW_B
#define IMG_B 861184        // 4 q * QPLANE_B
#define SLAB_B 14848        // 4 rows * ROW_B
#define SLAB_CH 928         // 16B chunks per slab

typedef __attribute__((ext_vector_type(4))) int int4v;

typedef const __attribute__((address_space(1))) unsigned int guint_t;
typedef __attribute__((address_space(3))) unsigned int luint_t;

__device__ __forceinline__ void gload16(void* lds, const void* g) {
    __builtin_amdgcn_global_load_lds((guint_t*)g, (luint_t*)lds, 16, 0, 0);
}

// quantize: x -> round(clamp(x*127/5)) as byte
__device__ __forceinline__ int q8(float f) {
    float c = fminf(fmaxf(f * 25.4f, -127.f), 127.f);
    return __float2int_rn(c) & 255;
}

// ---- pre-pass 1: NCHW f32 -> xq[n][q][row][col][64] i8, swizzle baked in ----
// physical 16B chunk pc of cell (row,col,q) holds ic range (pc ^ g(col))*16,
// g(col) = (col&3) ^ ((col>>2)&3)   [2-way bank aliasing on read = free, m136]
__global__ __launch_bounds__(256) void pad_i8(const float* __restrict__ x,
                                              unsigned char* __restrict__ xq) {
    __shared__ float lds[WW * 257];
    int bid = blockIdx.x;
    int n = bid / HP, h = bid % HP;
    bool hin = (h >= 1 && h <= HH);
    if (hin) {
        const float* src = x + (size_t)n * IN_C * (HH * WW) + (h - 1) * WW;
        for (int e = threadIdx.x; e < IN_C * WW; e += 256) {
            int ic = e / WW, w = e - ic * WW;
            lds[w * 257 + ic] = src[(size_t)ic * (HH * WW) + w];
        }
    }
    __syncthreads();
    unsigned char* dstn = xq + (size_t)n * IMG_B + (size_t)h * ROW_B;
    for (int e = threadIdx.x; e < 928; e += 256) {     // 4q * 58col * 4pc
        int q = e / 232, rem = e - q * 232;
        int col = rem >> 2, pc = rem & 3;
        int4v v = {0, 0, 0, 0};
        if (hin && col >= 1 && col <= WW) {
            int g = (col & 3) ^ ((col >> 2) & 3);
            int ic0 = q * 64 + ((pc ^ g) & 3) * 16;
            const float* p = &lds[(col - 1) * 257 + ic0];
#pragma unroll
            for (int wi = 0; wi < 4; ++wi) {
                int word = 0;
#pragma unroll
                for (int j = 0; j < 4; ++j) word |= q8(p[wi * 4 + j]) << (8 * j);
                v[wi] = word;
            }
        }
        *(int4v*)(dstn + (size_t)q * QPLANE_B + col * 64 + pc * 16) = v;
    }
}

// ---- pre-pass 2: OIHW f32 -> A-frag-ready i8, chunk i = [qt][s8][af][lane] ----
// oc = s8*32 + af*16 + (lane&15), ic = q*64 + (lane>>4)*16 + j, tap = qt%9
__global__ __launch_bounds__(256) void wconv(const float* __restrict__ w,
                                             unsigned char* __restrict__ wfr) {
    int i = blockIdx.x * 256 + threadIdx.x;      // 36864 chunks
    int lane = i & 63;
    int af = (i >> 6) & 1;
    int s8 = (i >> 7) & 7;
    int qt = i >> 10;                            // 0..35
    int tap = qt % 9, q = qt / 9;
    int oc = s8 * 32 + af * 16 + (lane & 15);
    int ic0 = q * 64 + (lane >> 4) * 16;
    int4v v;
#pragma unroll
    for (int wi = 0; wi < 4; ++wi) {
        int word = 0;
#pragma unroll
        for (int j = 0; j < 4; ++j)
            word |= (__float2int_rn(w[(size_t)oc * 2304 + (size_t)(ic0 + wi * 4 + j) * 9 + tap]) & 255)
                    << (8 * j);
        v[wi] = word;
    }
    *(int4v*)(wfr + (size_t)i * 16) = v;
}

// ---- main: i8 implicit-GEMM, 4-wave blocks (32oc x 112px), 3 blocks/CU, slab dbuf ----
__global__ __launch_bounds__(256, 3) void conv_i8(const unsigned char* __restrict__ xq,
                                                  const unsigned char* __restrict__ wfr,
                                                  float* __restrict__ out) {
    __shared__ unsigned char Xl[2][SLAB_B];

    const int tid = threadIdx.x;
    const int lane = tid & 63;
    const int wid = tid >> 6;

    const int bid = blockIdx.x;
    const int xcd = bid & 7, loc = bid >> 3;     // 4 images per XCD
    const int n = xcd * 4 + loc / 56;
    const int r = loc % 56;
    const int h = r & 1;                         // oc half
    const int rg = r >> 1;
    const int oh0 = rg * 2;
    const int pix0 = rg * 112;

    const unsigned char* xslab = xq + (size_t)n * IMG_B + (size_t)oh0 * ROW_B;

    const int rlo = lane & 15;
    const int kq = lane >> 4;
    int off[7][3];                               // cell byte offset incl. read swizzle
#pragma unroll
    for (int xf = 0; xf < 7; ++xf) {
        int pl = xf * 16 + rlo;
        int ohr = (pl >= 56) ? 1 : 0;
        int ow = pl - 56 * ohr;
#pragma unroll
        for (int kw = 0; kw < 3; ++kw) {
            int c = ow + kw;
            int g = (c & 3) ^ ((c >> 2) & 3);
            off[xf][kw] = (ohr * 58 + c) * 64 + ((kq ^ g) & 3) * 16;
        }
    }

    const int4v* wv = (const int4v*)wfr;
    const int abase = (h * 4 + wid) * 128 + lane;   // + qt*1024 (+af*64)

    int4v acc[2][7];
#pragma unroll
    for (int af = 0; af < 2; ++af)
#pragma unroll
        for (int xf = 0; xf < 7; ++xf) acc[af][xf] = {0, 0, 0, 0};

    int4v A0[2], A1[2], B[7];

#define LOAD_A(AF, QT)                                                         \
    {                                                                           \
        const int4v* p_ = wv + (QT) * 1024 + abase;                             \
        AF[0] = p_[0];                                                          \
        AF[1] = p_[64];                                                         \
    }

#define READ_B(TAP, SL)                                                        \
    {                                                                           \
        _Pragma("unroll")                                                       \
        for (int xf_ = 0; xf_ < 7; ++xf_)                                       \
            B[xf_] = *(const int4v*)(&(SL)[((TAP) / 3) * ROW_B + off[xf_][(TAP) % 3]]); \
    }

#define MMA(AF)                                                                \
    {                                                                           \
        __builtin_amdgcn_s_setprio(1);                                          \
        _Pragma("unroll")                                                       \
        for (int xf_ = 0; xf_ < 7; ++xf_)                                       \
            _Pragma("unroll")                                                   \
            for (int af_ = 0; af_ < 2; ++af_)                                   \
                acc[af_][xf_] = __builtin_amdgcn_mfma_i32_16x16x64_i8(          \
                    AF[af_], B[xf_], acc[af_][xf_], 0, 0, 0);                   \
        __builtin_amdgcn_s_setprio(0);                                          \
    }

    // ---- prologue: A(t=0) + slab q=0 (linear copy, swizzle pre-baked) ----
    LOAD_A(A0, 0);
#pragma unroll
    for (int k = 0; k < 3; ++k)
        gload16(&Xl[0][(tid + k * 256) * 16], xslab + (size_t)(tid + k * 256) * 16);
    if (tid < SLAB_CH - 768)
        gload16(&Xl[0][(tid + 768) * 16], xslab + (size_t)(tid + 768) * 16);
    asm volatile("s_waitcnt vmcnt(0)" ::: "memory");
    __builtin_amdgcn_s_barrier();
    __builtin_amdgcn_sched_barrier(0);

#pragma unroll
    for (int q = 0; q < 4; ++q) {
        const unsigned char* SL = Xl[q & 1];
        unsigned char* NS = Xl[(q & 1) ^ 1];
        const unsigned char* nsrc = xslab + (size_t)(q + 1) * QPLANE_B;
#pragma unroll
        for (int s = 0; s < 9; ++s) {
            const int t = q * 9 + s;
            if (t < 35) {
                if (t & 1) { LOAD_A(A0, t + 1); } else { LOAD_A(A1, t + 1); }
            }
            // drip-prefetch next q's slab at steps 2..5 (>=3 steps of cover)
            if (q < 3 && s >= 2 && s <= 5) {
                const int k = s - 2;
                if (k < 3)
                    gload16(&NS[(tid + k * 256) * 16], nsrc + (size_t)(tid + k * 256) * 16);
                else if (tid < SLAB_CH - 768)
                    gload16(&NS[(tid + 768) * 16], nsrc + (size_t)(tid + 768) * 16);
            }
            READ_B(s, SL);
            __builtin_amdgcn_sched_barrier(0);
            if (t & 1) { MMA(A1); } else { MMA(A0); }
        }
        if (q < 3) {
            asm volatile("s_waitcnt vmcnt(0)" ::: "memory");   // prefetches long done
            __builtin_amdgcn_s_barrier();
        }
    }

    // ---- epilogue: col = lane&15 -> pixel, row = kq*4+reg -> oc; dequant ----
    const float S = 5.0f / 127.0f;
    float* outn = out + (size_t)n * (OUT_C * HH * WW) + pix0 + rlo;
    const int ocb = h * 128 + wid * 32 + kq * 4;
#pragma unroll
    for (int af = 0; af < 2; ++af)
#pragma unroll
        for (int rr = 0; rr < 4; ++rr) {
            float* op = outn + (size_t)(ocb + af * 16 + rr) * (HH * WW);
#pragma unroll
            for (int xf = 0; xf < 7; ++xf)
                op[xf * 16] = (float)acc[af][xf][rr] * S;
        }
}

extern "C" void kernel_launch(void* const* d_in, const int* in_sizes, int n_in,
                              void* d_out, int out_size, void* d_ws, size_t ws_size,
                              hipStream_t stream) {
    const float* x = (const float*)d_in[0];
    const float* wgt = (const float*)d_in[1];
    float* out = (float*)d_out;

    unsigned char* xqb = (unsigned char*)d_ws;                     // 27.6 MB
    unsigned char* wfr = xqb + (size_t)NB * IMG_B;                 // 0.59 MB

    hipLaunchKernelGGL(pad_i8, dim3(NB * HP), dim3(256), 0, stream, x, xqb);
    hipLaunchKernelGGL(wconv, dim3(144), dim3(256), 0, stream, wgt, wfr);
    hipLaunchKernelGGL(conv_i8, dim3(NTILE), dim3(256), 0, stream, xqb, wfr, out);
}